// Round 1
// baseline (328.133 us; speedup 1.0000x reference)
//
#include <hip/hip_runtime.h>
#include <stdint.h>

// Problem constants
#define B_BATCH 2048     // batch rows (softmax columns here)
#define D_K     128      // embedding dim = GEMM K
#define N_ENT   100000   // entities = GEMM M (reduction axis of logsumexp)
#define BM      128      // entities per chunk (block M-tile)
#define NCHUNK  ((N_ENT + BM - 1) / BM)   // 782
#define TB      128      // batch columns per tile
#define NTILE   (B_BATCH / TB)            // 16

typedef __attribute__((ext_vector_type(8))) __bf16 bf16x8;
typedef __attribute__((ext_vector_type(8))) short  short8;
typedef __attribute__((ext_vector_type(4))) float  f32x4;

__device__ __forceinline__ short f2bf(float x) {
  // RNE fp32 -> bf16
  unsigned int u = __float_as_uint(x);
  unsigned int r = (u + 0x7fffu + ((u >> 16) & 1u)) >> 16;
  return (short)r;
}

__device__ __forceinline__ short8 pack8(f32x4 a, f32x4 b) {
  short8 v;
  v[0] = f2bf(a[0]); v[1] = f2bf(a[1]); v[2] = f2bf(a[2]); v[3] = f2bf(a[3]);
  v[4] = f2bf(b[0]); v[5] = f2bf(b[1]); v[6] = f2bf(b[2]); v[7] = f2bf(b[3]);
  return v;
}

// online-logsumexp merge in base-2 domain. -1e30 sentinel for "empty";
// exp2f(-1e30 - finite) underflows to 0, exp2f(0)=1 pairs with s=0 -> safe, no NaN.
__device__ __forceinline__ void lse_merge(float& m, float& s, float mo, float so) {
  float mm = fmaxf(m, mo);
  s = s * exp2f(m - mm) + so * exp2f(mo - mm);
  m = mm;
}

// ---------------------------------------------------------------------------
// Main kernel: per block, one (or more) 128-entity chunk(s). For each chunk:
//  - stage E-chunk fp32->bf16 into XOR-swizzled LDS, load A-fragments resident
//  - loop 16 batch tiles of 128 cols: stage X tile, 64 MFMAs/wave, fused
//    online-(max,sumexp) epilogue over the 128 entity rows per column
//  - running per-column (m,s) lives in LDS; written once as block partials
// LDS swizzle: elem_off ^= (row&7)<<3 (ushort units) == byte ^ (row&7)<<4,
// applied on both write and read (G4: breaks the 256B-row-stride bank conflict).
// ---------------------------------------------------------------------------
__global__ __launch_bounds__(256, 2)
void fused_lse_kernel(const float* __restrict__ X,     // [2048][128] batch embeddings
                      const float* __restrict__ E,     // [100000][128] entity embs
                      const float* __restrict__ bias,  // [100000]
                      float2* __restrict__ P,          // [NB][2048] partials (m2, s)
                      int NB)
{
  __shared__ __align__(16) unsigned short Tld[BM * D_K]; // 32KB shared stage tile (E then X)
  __shared__ float2 run[B_BATCH];                        // 16KB running (m,s) per batch col
  __shared__ float  Blds[BM];                            // bias for chunk rows
  __shared__ float2 comb[2][TB];                         // cross-wave (wm) combine

  const int t    = threadIdx.x;
  const int lane = t & 63;
  const int w    = t >> 6;
  const int wm   = w & 1;        // wave row-half (entities)
  const int wn   = w >> 1;       // wave col-half (batch)
  const int lg   = lane >> 4;    // lane group 0..3
  const int l15  = lane & 15;
  const float LOG2E = 1.4426950408889634f;

  for (int j = t; j < B_BATCH; j += 256) run[j] = make_float2(-1e30f, 0.f);

  for (int g = blockIdx.x; g < NCHUNK; g += NB) {
    const int ent0       = g * BM;
    const int rows_valid = min(BM, N_ENT - ent0);

    __syncthreads();   // run init / previous iteration's Tld+Blds readers done

    // ---- stage E chunk (bf16, swizzled) + bias ----
    #pragma unroll
    for (int i = 0; i < 8; ++i) {
      int c = t + 256 * i;            // 16B-chunk index, 2048 total
      int row = c >> 4, sub = c & 15; // row in tile, 8-elem group in row
      f32x4 f0 = {0.f,0.f,0.f,0.f}, f1 = {0.f,0.f,0.f,0.f};
      if (row < rows_valid) {
        const float* src = E + (size_t)(ent0 + row) * D_K + sub * 8;
        f0 = *(const f32x4*)src;
        f1 = *(const f32x4*)(src + 4);
      }
      int du = row * D_K + ((sub * 8) ^ ((row & 7) << 3));
      *(short8*)&Tld[du] = pack8(f0, f1);
    }
    if (t < BM) Blds[t] = (t < rows_valid) ? bias[ent0 + t] : 0.f;
    __syncthreads();

    // ---- resident A fragments: 4 m-frags x 4 k-steps (64 VGPR) ----
    bf16x8 Areg[4][4];
    #pragma unroll
    for (int mi = 0; mi < 4; ++mi)
      #pragma unroll
      for (int kk = 0; kk < 4; ++kk) {
        int row = wm * 64 + mi * 16 + l15;
        int off = row * D_K + (((kk * 32) + lg * 8) ^ ((row & 7) << 3));
        Areg[mi][kk] = __builtin_bit_cast(bf16x8, *(const short8*)&Tld[off]);
      }
    // per-thread row bias + validity (rows: wm*64 + mi*16 + lg*4 + r)
    float brow[16];
    bool  vrow[16];
    #pragma unroll
    for (int mi = 0; mi < 4; ++mi)
      #pragma unroll
      for (int r = 0; r < 4; ++r) {
        int rl = wm * 64 + mi * 16 + lg * 4 + r;
        vrow[mi * 4 + r] = (rl < rows_valid);
        brow[mi * 4 + r] = Blds[rl];
      }
    __syncthreads();  // all waves done reading E from Tld

    // ---- batch tiles ----
    for (int it = 0; it < NTILE; ++it) {
      const float* xb = X + (size_t)it * TB * D_K;
      #pragma unroll
      for (int i = 0; i < 8; ++i) {
        int c = t + 256 * i;
        int row = c >> 4, sub = c & 15;
        const f32x4* src = (const f32x4*)(xb + row * D_K + sub * 8);
        f32x4 f0 = src[0], f1 = src[1];
        *(short8*)&Tld[row * D_K + ((sub * 8) ^ ((row & 7) << 3))] = pack8(f0, f1);
      }
      __syncthreads();

      f32x4 acc[4][4];
      #pragma unroll
      for (int mi = 0; mi < 4; ++mi)
        #pragma unroll
        for (int nj = 0; nj < 4; ++nj)
          acc[mi][nj] = (f32x4){0.f, 0.f, 0.f, 0.f};

      #pragma unroll
      for (int kk = 0; kk < 4; ++kk) {
        bf16x8 bfr[4];
        #pragma unroll
        for (int nj = 0; nj < 4; ++nj) {
          int row = wn * 64 + nj * 16 + l15;   // batch row within tile
          int off = row * D_K + (((kk * 32) + lg * 8) ^ ((row & 7) << 3));
          bfr[nj] = __builtin_bit_cast(bf16x8, *(const short8*)&Tld[off]);
        }
        #pragma unroll
        for (int mi = 0; mi < 4; ++mi)
          #pragma unroll
          for (int nj = 0; nj < 4; ++nj)
            acc[mi][nj] = __builtin_amdgcn_mfma_f32_16x16x32_bf16(
                Areg[mi][kk], bfr[nj], acc[mi][nj], 0, 0, 0);
      }

      // ---- fused epilogue: per-column (max, sumexp) over 128 entity rows ----
      // D layout: col = lane&15, row = mi*16 + lg*4 + r  (verified m89/m91)
      #pragma unroll
      for (int nj = 0; nj < 4; ++nj) {
        float m = -1e30f;
        float lb[16];
        #pragma unroll
        for (int mi = 0; mi < 4; ++mi)
          #pragma unroll
          for (int r = 0; r < 4; ++r) {
            int idx = mi * 4 + r;
            float l = (acc[mi][nj][r] + brow[idx]) * LOG2E;
            lb[idx] = vrow[idx] ? l : -1e30f;
            m = fmaxf(m, lb[idx]);
          }
        float s = 0.f;
        #pragma unroll
        for (int idx = 0; idx < 16; ++idx)
          s += vrow[idx] ? exp2f(lb[idx] - m) : 0.f;
        // lanes {c, c+16, c+32, c+48} share a column -> xor-16, xor-32
        #pragma unroll
        for (int sh = 16; sh <= 32; sh <<= 1) {
          float mo = __shfl_xor(m, sh);
          float so = __shfl_xor(s, sh);
          lse_merge(m, s, mo, so);
        }
        if (lane < 16) comb[wm][wn * 64 + nj * 16 + lane] = make_float2(m, s);
      }
      __syncthreads();
      if (t < TB) {  // merge the two wm-halves, fold into running state
        float2 a = comb[0][t], b2 = comb[1][t];
        float m = a.x, s = a.y;
        lse_merge(m, s, b2.x, b2.y);
        float2 rr = run[it * TB + t];
        lse_merge(rr.x, rr.y, m, s);
        run[it * TB + t] = rr;
      }
      __syncthreads();  // merge done + MFMA readers done -> Tld reusable
    }
  }

  __syncthreads();
  for (int j = t; j < B_BATCH; j += 256)
    P[(size_t)blockIdx.x * B_BATCH + j] = run[j];
}

// ---------------------------------------------------------------------------
// Reduce: per batch col, combine NB partials; compute exact fp32 target logit
// dot(X[b], E[y[b]]) + bias[y[b]]; emit per-row loss.
// ---------------------------------------------------------------------------
__global__ __launch_bounds__(256)
void reduce_kernel(const float2* __restrict__ P, int NB,
                   const float* __restrict__ X, const float* __restrict__ E,
                   const float* __restrict__ bias, const int* __restrict__ y,
                   float* __restrict__ loss)
{
  int t  = threadIdx.x;
  int tx = t >> 2;            // 0..63 -> column
  int ty = t & 3;             // 0..3  -> partial stripe
  int b  = blockIdx.x * 64 + tx;

  float m = -1e30f, s = 0.f;
  for (int g = ty; g < NB; g += 4) {
    float2 p = P[(size_t)g * B_BATCH + b];
    lse_merge(m, s, p.x, p.y);
  }

  int yb = y[b];
  const f32x4* xr = (const f32x4*)(X + (size_t)b  * D_K);
  const f32x4* er = (const f32x4*)(E + (size_t)yb * D_K);
  float dot = 0.f;
  #pragma unroll
  for (int j = 0; j < 8; ++j) {
    f32x4 a = xr[ty * 8 + j], e = er[ty * 8 + j];
    dot += a[0]*e[0] + a[1]*e[1] + a[2]*e[2] + a[3]*e[3];
  }

  #pragma unroll
  for (int sh = 1; sh <= 2; sh <<= 1) {
    float mo = __shfl_xor(m, sh);
    float so = __shfl_xor(s, sh);
    lse_merge(m, s, mo, so);
    dot += __shfl_xor(dot, sh);
  }
  if (ty == 0)
    loss[b] = 0.6931471805599453f * (m + log2f(s)) - (dot + bias[yb]);
}

__global__ __launch_bounds__(256)
void final_kernel(const float* __restrict__ loss, float* __restrict__ out)
{
  __shared__ float wsum[4];
  int t = threadIdx.x;
  float s = 0.f;
  for (int j = t; j < B_BATCH; j += 256) s += loss[j];
  #pragma unroll
  for (int sh = 1; sh <= 32; sh <<= 1) s += __shfl_xor(s, sh);
  if ((t & 63) == 0) wsum[t >> 6] = s;
  __syncthreads();
  if (t == 0) out[0] = (wsum[0] + wsum[1] + wsum[2] + wsum[3]) / (float)B_BATCH;
}

extern "C" void kernel_launch(void* const* d_in, const int* in_sizes, int n_in,
                              void* d_out, int out_size, void* d_ws, size_t ws_size,
                              hipStream_t stream)
{
  (void)in_sizes; (void)n_in; (void)out_size;
  const float* X    = (const float*)d_in[0];   // entity_embeddings [2048,128]
  const float* E    = (const float*)d_in[1];   // entity_embs [100000,128]
  const float* bias = (const float*)d_in[2];   // rec_entity_bias [100000]
  const int*   y    = (const int*)d_in[3];     // labels [2048]
  float* out = (float*)d_out;

  // workspace: P = float2[NB][2048], then loss = float[2048]
  const size_t lossBytes = (size_t)B_BATCH * sizeof(float);
  int nbMax = (int)((ws_size > lossBytes ? ws_size - lossBytes : 0) /
                    ((size_t)B_BATCH * sizeof(float2)));
  int NB = NCHUNK;
  if (NB > nbMax) NB = nbMax;
  if (NB < 1) NB = 1;

  float2* P    = (float2*)d_ws;
  float*  loss = (float*)((char*)d_ws + (size_t)NB * B_BATCH * sizeof(float2));

  fused_lse_kernel<<<NB, 256, 0, stream>>>(X, E, bias, P, NB);
  reduce_kernel<<<B_BATCH / 64, 256, 0, stream>>>(P, NB, X, E, bias, y, loss);
  final_kernel<<<1, 256, 0, stream>>>(loss, out);
}